// Round 4
// baseline (251.470 us; speedup 1.0000x reference)
//
#include <hip/hip_runtime.h>
#include <hip/hip_bf16.h>

// MHA: weight pre-convert -> fused qkv proj (R9/R11 64x128) -> flash attention
// (transposed-S, fixed-shift log2 softmax, ones-MFMA denominator, KV-TILE 128
// with per-64 sub-tiling, hoisted LDS bases, running global ptrs)
// -> out proj.
// R13..R16: flash restructured 4 waves x 32q -> 8 waves x 16q (512 thr) to
// lift occupancy 2->4 waves/SIMD (latency-bound theory); s_setprio(1) around
// MFMA clusters (T5). GEMMs untouched (control). Resubmitted unchanged (never
// ran: GPU acquisition timeout four rounds).

typedef __attribute__((ext_vector_type(8))) short bf16x8;   // 8 bf16 (MFMA A/B frag)
typedef __attribute__((ext_vector_type(4))) float f32x4;    // MFMA C/D frag

#define SEQ  4096
#define DM   512
#define FPAD 72    // Qs/Ks/Ps row stride (shorts)
#define VPAD 136   // Vs row stride (shorts): 64 dv x 128 kv + pad
#define QSCALE 0.18033688011112042f   // 0.125 * log2(e): scores in log2 domain
#define FSHIFT 16.0f                  // fixed softmax shift (log2 domain)

__device__ inline float fast_exp2(float x) {   // raw v_exp_f32: D = 2^S0
#if __has_builtin(__builtin_amdgcn_exp2f)
    return __builtin_amdgcn_exp2f(x);
#else
    return __expf(x * 0.69314718056f);
#endif
}

__device__ inline unsigned pk2(float x, float y) {   // 2x f32 -> packed bf16 RNE
#if __has_builtin(__builtin_amdgcn_cvt_pk_bf16_f32)
    typedef __attribute__((ext_vector_type(2))) __bf16 bf16x2_t;
    bf16x2_t h = __builtin_amdgcn_cvt_pk_bf16_f32(x, y);
    return *(unsigned*)&h;
#else
    unsigned ux = __float_as_uint(x);
    unsigned uy = __float_as_uint(y);
    ux += 0x7fff + ((ux >> 16) & 1);      // finite-safe RNE (all inputs finite)
    uy += 0x7fff + ((uy >> 16) & 1);
    return (ux >> 16) | (uy & 0xffff0000u);
#endif
}

// Convert the 4 weight matrices (512x512 fp32) to bf16 once.
__global__ __launch_bounds__(256) void cvt_w(
    const float* __restrict__ w0, const float* __restrict__ w1,
    const float* __restrict__ w2, const float* __restrict__ w3,
    __hip_bfloat16* __restrict__ o0, __hip_bfloat16* __restrict__ o1,
    __hip_bfloat16* __restrict__ o2, __hip_bfloat16* __restrict__ o3)
{
    const float* w = (blockIdx.y == 0) ? w0 : (blockIdx.y == 1) ? w1
                   : (blockIdx.y == 2) ? w2 : w3;
    __hip_bfloat16* o = (blockIdx.y == 0) ? o0 : (blockIdx.y == 1) ? o1
                      : (blockIdx.y == 2) ? o2 : o3;
    const int i = (blockIdx.x * 256 + threadIdx.x) * 4;   // < 262144
    float4 v = *(const float4*)&w[i];
    uint2 p;
    p.x = pk2(v.x, v.y);
    p.y = pk2(v.z, v.w);
    *(uint2*)&((unsigned short*)o)[i] = p;
}

// Fused QKV projection (R9 structure), 64(M) x 128(N) tile, z selects stream.
__global__ __launch_bounds__(256) void qkv_proj(
    const float* __restrict__ Xq, const float* __restrict__ Xk, const float* __restrict__ Xv,
    const __hip_bfloat16* __restrict__ Wq16, const __hip_bfloat16* __restrict__ Wk16,
    const __hip_bfloat16* __restrict__ Wv16,
    const float* __restrict__ bq, const float* __restrict__ bk, const float* __restrict__ bv,
    __hip_bfloat16* __restrict__ Oq, __hip_bfloat16* __restrict__ Ok,
    __hip_bfloat16* __restrict__ Ovt)
{
    const int z = blockIdx.z;
    const float* A          = (z == 0) ? Xq : (z == 1) ? Xk : Xv;
    const __hip_bfloat16* W = (z == 0) ? Wq16 : (z == 1) ? Wk16 : Wv16;
    const float* bias       = (z == 0) ? bq : (z == 1) ? bk : bv;

    __shared__ __align__(16) short As[64 * 32];
    __shared__ __align__(16) short Ws2[128 * 32];

    const int bm   = blockIdx.x * 64;
    const int bn   = blockIdx.y * 128;
    const int tid  = threadIdx.x;
    const int wave = tid >> 6;
    const int lane = tid & 63;
    const int quad = lane >> 4;
    const int l16  = lane & 15;

    const int srow = tid >> 2;          // 0..63
    const int scol = (tid & 3) * 8;     // 0/8/16/24

    f32x4 acc[8] = {};

    float4 a0 = *(const float4*)&A[(size_t)(bm + srow) * DM + scol];
    float4 a1 = *(const float4*)&A[(size_t)(bm + srow) * DM + scol + 4];
    bf16x8 w0 = *(const bf16x8*)&W[(size_t)(bn + srow) * DM + scol];
    bf16x8 w1 = *(const bf16x8*)&W[(size_t)(bn + srow + 64) * DM + scol];

    for (int k0 = 0; k0 < DM; k0 += 32) {
        uint4 pa = {pk2(a0.x, a0.y), pk2(a0.z, a0.w), pk2(a1.x, a1.y), pk2(a1.z, a1.w)};

        __syncthreads();
        *(uint4*)&As[srow * 32 + scol] = pa;
        *(bf16x8*)&Ws2[srow * 32 + scol] = w0;
        *(bf16x8*)&Ws2[(srow + 64) * 32 + scol] = w1;
        __syncthreads();

        if (k0 + 32 < DM) {
            a0 = *(const float4*)&A[(size_t)(bm + srow) * DM + k0 + 32 + scol];
            a1 = *(const float4*)&A[(size_t)(bm + srow) * DM + k0 + 32 + scol + 4];
            w0 = *(const bf16x8*)&W[(size_t)(bn + srow) * DM + k0 + 32 + scol];
            w1 = *(const bf16x8*)&W[(size_t)(bn + srow + 64) * DM + k0 + 32 + scol];
        }

        bf16x8 a = *(bf16x8*)&As[(wave * 16 + l16) * 32 + quad * 8];
#pragma unroll
        for (int nt = 0; nt < 8; nt++) {
            bf16x8 b = *(bf16x8*)&Ws2[(nt * 16 + l16) * 32 + quad * 8];
            acc[nt] = __builtin_amdgcn_mfma_f32_16x16x32_bf16(a, b, acc[nt], 0, 0, 0);
        }
    }

    // C/D layout: col = lane&15 (= n), row = quad*4 + r (= m)
    if (z == 2) {
        const int row0 = bm + wave * 16 + quad * 4;
        const int b    = row0 >> 12;
        const int seq0 = row0 & 4095;
        unsigned short* Vt = (unsigned short*)Ovt;
#pragma unroll
        for (int nt = 0; nt < 8; nt++) {
            const int col = bn + nt * 16 + l16;
            const float bv_ = bias[col];
            uint2 pk;
            pk.x = pk2(acc[nt][0] + bv_, acc[nt][1] + bv_);
            pk.y = pk2(acc[nt][2] + bv_, acc[nt][3] + bv_);
            *(uint2*)&Vt[((size_t)(b * 512 + col)) * 4096 + seq0] = pk;
        }
    } else {
        unsigned short* C = (unsigned short*)((z == 0) ? Oq : Ok);
        const float scale = (z == 0) ? QSCALE : 1.0f;
        const size_t row0 = bm + wave * 16 + quad * 4;
#pragma unroll
        for (int nt = 0; nt < 8; nt++) {
            const int col = bn + nt * 16 + l16;
            const float bv_ = bias[col];
            unsigned u01 = pk2((acc[nt][0] + bv_) * scale, (acc[nt][1] + bv_) * scale);
            unsigned u23 = pk2((acc[nt][2] + bv_) * scale, (acc[nt][3] + bv_) * scale);
            C[(row0 + 0) * DM + col] = (unsigned short)(u01 & 0xffff);
            C[(row0 + 1) * DM + col] = (unsigned short)(u01 >> 16);
            C[(row0 + 2) * DM + col] = (unsigned short)(u23 & 0xffff);
            C[(row0 + 3) * DM + col] = (unsigned short)(u23 >> 16);
        }
    }
}

// Flash attention: transposed-S, fixed-shift log2 softmax, 16 q/wave x 8 waves,
// KV tile = 128 (two 64-kv sub-tiles sharing one staging round + barrier pair).
__global__ __launch_bounds__(512, 4) void flash_attn(
    const __hip_bfloat16* __restrict__ Q,
    const __hip_bfloat16* __restrict__ K,
    const __hip_bfloat16* __restrict__ Vt,
    __hip_bfloat16* __restrict__ O)
{
    __shared__ __align__(16) short Qs[128 * FPAD];     // [q][d]; Ps aliases per-wave strips
    __shared__ __align__(16) short Ks[128 * FPAD];     // [kv 128][d]
    __shared__ __align__(16) short Vs[64 * VPAD];      // [dv][kv 128] (pre-transposed)

    const int q0 = blockIdx.x * 128;
    const int bh = blockIdx.y;

    const int tid  = threadIdx.x;
    const int wave = tid >> 6;      // 0..7
    const int lane = tid & 63;
    const int quad = lane >> 4;
    const int l16  = lane & 15;
    const int qw   = wave * 16;     // wave's q base within block

    const __hip_bfloat16* Qb = Q + (size_t)(bh >> 3) * SEQ * DM + (bh & 7) * 64;
    const __hip_bfloat16* Kb = K + (size_t)(bh >> 3) * SEQ * DM + (bh & 7) * 64;
    const __hip_bfloat16* Vb = Vt + (size_t)bh * 64 * SEQ;
    __hip_bfloat16*       Ob = O + (size_t)(bh >> 3) * SEQ * DM + (bh & 7) * 64;

    // staging maps (512 threads)
    const int kr = tid >> 3;            // 0..63: K/Q rows kr + i*64, cols (tid&7)*8
    const int kc = (tid & 7) * 8;
    const int vr = tid >> 4;            // 0..31: V rows vr + i*32, cols (tid&15)*8
    const int vc = (tid & 15) * 8;

    // Q stage (once): 128 rows
#pragma unroll
    for (int i = 0; i < 2; i++)
        *(bf16x8*)&Qs[(kr + i * 64) * FPAD + kc] =
            *(const bf16x8*)&Qb[(size_t)(q0 + kr + i * 64) * DM + kc];

    // running global prefetch pointers (advance by constants)
    const __hip_bfloat16* kg = Kb + (size_t)kr * DM + kc;
    const __hip_bfloat16* vg = Vb + (size_t)vr * SEQ + vc;

    bf16x8 kp[2], vp[2];
#pragma unroll
    for (int i = 0; i < 2; i++) {
        kp[i] = *(const bf16x8*)(kg + (size_t)i * 64 * DM);
        vp[i] = *(const bf16x8*)(vg + (size_t)i * 32 * SEQ);
    }

    __syncthreads();   // Qs staged

    // hoist loop-invariant Q B-frags: bq[ks], q = qw + l16
    bf16x8 bq[2];
#pragma unroll
    for (int ks = 0; ks < 2; ks++)
        bq[ks] = *(bf16x8*)&Qs[(qw + l16) * FPAD + ks * 32 + quad * 8];

    bf16x8 ones;
#pragma unroll
    for (int j = 0; j < 8; j++) ones[j] = (short)0x3F80;

    // hoisted LDS base pointers (constant offsets inside the loop)
    const short* ksb = &Ks[l16 * FPAD + quad * 8];
    const short* vsb = &Vs[l16 * VPAD + quad * 8];
    // wave's P strip aliases its own Qs rows [qw, qw+16) (bq already hoisted;
    // same-wave DS ordering via lgkmcnt)
    const short* psb = &Qs[(qw + l16) * FPAD + quad * 8];   // bp reads
    short*       psw = &Qs[(qw + l16) * FPAD + quad * 4];   // P writes

    f32x4 oacc[4] = {};   // O^T
    f32x4 lacc = {};      // denominator

    for (int kv0 = 0; kv0 < SEQ; kv0 += 128) {
        __syncthreads();
#pragma unroll
        for (int i = 0; i < 2; i++) {
            *(bf16x8*)&Ks[(kr + i * 64) * FPAD + kc] = kp[i];
            *(bf16x8*)&Vs[(vr + i * 32) * VPAD + vc] = vp[i];
        }
        __syncthreads();

        kg += (size_t)128 * DM;
        vg += 128;
        if (kv0 + 128 < SEQ) {
#pragma unroll
            for (int i = 0; i < 2; i++) {
                kp[i] = *(const bf16x8*)(kg + (size_t)i * 64 * DM);
                vp[i] = *(const bf16x8*)(vg + (size_t)i * 32 * SEQ);
            }
        }

#pragma unroll
        for (int kh = 0; kh < 2; kh++) {
            // S^T = K Q^T for this 64-kv half
            f32x4 s[4] = {};
            __builtin_amdgcn_s_setprio(1);
#pragma unroll
            for (int ks = 0; ks < 2; ks++) {
#pragma unroll
                for (int nt = 0; nt < 4; nt++) {
                    bf16x8 ak = *(const bf16x8*)&ksb[(kh * 64 + nt * 16) * FPAD + ks * 32];
                    s[nt] = __builtin_amdgcn_mfma_f32_16x16x32_bf16(
                        ak, bq[ks], s[nt], 0, 0, 0);
                }
            }
            __builtin_amdgcn_s_setprio(0);

            // P = 2^(s - 16): exact by shift-invariance
#pragma unroll
            for (int nt = 0; nt < 4; nt++) {
                float p0 = fast_exp2(s[nt][0] - FSHIFT);
                float p1 = fast_exp2(s[nt][1] - FSHIFT);
                float p2 = fast_exp2(s[nt][2] - FSHIFT);
                float p3 = fast_exp2(s[nt][3] - FSHIFT);
                uint2 pk;
                pk.x = pk2(p0, p1);
                pk.y = pk2(p2, p3);
                *(uint2*)&psw[nt * 16] = pk;
            }

            // O^T += V^T P^T; l += ones P^T  (Ps per-wave; lgkmcnt orders same-wave DS)
            __builtin_amdgcn_s_setprio(1);
#pragma unroll
            for (int ks = 0; ks < 2; ks++) {
                bf16x8 av[4];
#pragma unroll
                for (int dt = 0; dt < 4; dt++)
                    av[dt] = *(const bf16x8*)&vsb[dt * 16 * VPAD + kh * 64 + ks * 32];
                bf16x8 bp = *(const bf16x8*)&psb[ks * 32];
#pragma unroll
                for (int dt = 0; dt < 4; dt++)
                    oacc[dt] = __builtin_amdgcn_mfma_f32_16x16x32_bf16(
                        av[dt], bp, oacc[dt], 0, 0, 0);
                lacc = __builtin_amdgcn_mfma_f32_16x16x32_bf16(
                    ones, bp, lacc, 0, 0, 0);
            }
            __builtin_amdgcn_s_setprio(0);
        }
    }

    // epilogue: lane owns q = q0 + qw + l16; 4 consecutive dv per dt
    unsigned short* Op = (unsigned short*)Ob;
    const float inv = 1.0f / lacc[0];
    const int q = q0 + qw + l16;
#pragma unroll
    for (int dt = 0; dt < 4; dt++) {
        uint2 ov;
        ov.x = pk2(oacc[dt][0] * inv, oacc[dt][1] * inv);
        ov.y = pk2(oacc[dt][2] * inv, oacc[dt][3] * inv);
        *(uint2*)&Op[(size_t)q * DM + dt * 16 + quad * 4] = ov;
    }
}

// Output projection (R9 structure), 64x128 tile: A bf16, W bf16, C fp32.
__global__ __launch_bounds__(256) void out_proj(
    const __hip_bfloat16* __restrict__ A,
    const __hip_bfloat16* __restrict__ W,
    const float* __restrict__ bias,
    float* __restrict__ C)
{
    __shared__ __align__(16) short As[64 * 32];
    __shared__ __align__(16) short Ws2[128 * 32];

    const int bm   = blockIdx.x * 64;
    const int bn   = blockIdx.y * 128;
    const int tid  = threadIdx.x;
    const int wave = tid >> 6;
    const int lane = tid & 63;
    const int quad = lane >> 4;
    const int l16  = lane & 15;

    const int srow = tid >> 2;
    const int scol = (tid & 3) * 8;

    f32x4 acc[8] = {};

    bf16x8 ap = *(const bf16x8*)&A[(size_t)(bm + srow) * DM + scol];
    bf16x8 w0 = *(const bf16x8*)&W[(size_t)(bn + srow) * DM + scol];
    bf16x8 w1 = *(const bf16x8*)&W[(size_t)(bn + srow + 64) * DM + scol];

    for (int k0 = 0; k0 < DM; k0 += 32) {
        __syncthreads();
        *(bf16x8*)&As[srow * 32 + scol] = ap;
        *(bf16x8*)&Ws2[srow * 32 + scol] = w0;
        *(bf16x8*)&Ws2[(srow + 64) * 32 + scol] = w1;
        __syncthreads();

        if (k0 + 32 < DM) {
            ap = *(const bf16x8*)&A[(size_t)(bm + srow) * DM + k0 + 32 + scol];
            w0 = *(const bf16x8*)&W[(size_t)(bn + srow) * DM + k0 + 32 + scol];
            w1 = *(const bf16x8*)&W[(size_t)(bn + srow + 64) * DM + k0 + 32 + scol];
        }

        bf16x8 a = *(bf16x8*)&As[(wave * 16 + l16) * 32 + quad * 8];
#pragma unroll
        for (int nt = 0; nt < 8; nt++) {
            bf16x8 b = *(bf16x8*)&Ws2[(nt * 16 + l16) * 32 + quad * 8];
            acc[nt] = __builtin_amdgcn_mfma_f32_16x16x32_bf16(a, b, acc[nt], 0, 0, 0);
        }
    }

#pragma unroll
    for (int nt = 0; nt < 8; nt++) {
        const int col = bn + nt * 16 + l16;
        const float bv_ = bias[col];
#pragma unroll
        for (int r = 0; r < 4; r++) {
            const int row = bm + wave * 16 + quad * 4 + r;
            C[(size_t)row * DM + col] = acc[nt][r] + bv_;
        }
    }
}

extern "C" void kernel_launch(void* const* d_in, const int* in_sizes, int n_in,
                              void* d_out, int out_size, void* d_ws, size_t ws_size,
                              hipStream_t stream) {
    const float* queries = (const float*)d_in[0];
    const float* keys    = (const float*)d_in[1];
    const float* values  = (const float*)d_in[2];
    const float* Wq = (const float*)d_in[3];
    const float* bq = (const float*)d_in[4];
    const float* Wk = (const float*)d_in[5];
    const float* bk = (const float*)d_in[6];
    const float* Wv = (const float*)d_in[7];
    const float* bv = (const float*)d_in[8];
    const float* Wo = (const float*)d_in[9];
    const float* bo = (const float*)d_in[10];
    float* out = (float*)d_out;

    const size_t MS = (size_t)2 * SEQ * DM;   // 4.19M elems
    const size_t WN = (size_t)DM * DM;        // 262144 elems
    __hip_bfloat16* q_ws  = (__hip_bfloat16*)d_ws;
    __hip_bfloat16* k_ws  = q_ws + MS;
    __hip_bfloat16* vt_ws = k_ws + MS;        // [16][64][4096]
    __hip_bfloat16* o_ws  = vt_ws + MS;
    __hip_bfloat16* wq16  = o_ws + MS;
    __hip_bfloat16* wk16  = wq16 + WN;
    __hip_bfloat16* wv16  = wk16 + WN;
    __hip_bfloat16* wo16  = wv16 + WN;

    dim3 blk(256);

    cvt_w<<<dim3(256, 4), blk, 0, stream>>>(Wq, Wk, Wv, Wo, wq16, wk16, wv16, wo16);

    qkv_proj<<<dim3(128, 4, 3), blk, 0, stream>>>(
        queries, keys, values, wq16, wk16, wv16, bq, bk, bv, q_ws, k_ws, vt_ws);

    flash_attn<<<dim3(32, 16), dim3(512), 0, stream>>>(q_ws, k_ws, vt_ws, o_ws);

    out_proj<<<dim3(128, 4), blk, 0, stream>>>(o_ws, wo16, bo, out);
}

// Round 8
// 251.333 us; speedup vs baseline: 1.0005x; 1.0005x over previous
//
#include <hip/hip_runtime.h>
#include <hip/hip_bf16.h>

// MHA: weight pre-convert -> fused qkv proj (R9/R11 64x128) -> flash attention
// -> out proj.
// R17..R20: flash rebuilt for LDS-throughput (R13 post-mortem: ~90% LDS-occupied,
// 23M bank-conflict cycles, HBM 8%, MfmaUtil 27%):
//   * 32x32x16 MFMA (2x FLOP per LDS fragment byte)
//   * 32 q/wave x 4 waves (128 q/block, grid unchanged)
//   * Q direct global->reg (no Qs LDS), P in-register via permlane32_swap
//     (no P LDS round trip), denominator via VALU sum of rounded P
//     (same bf16 terms as the old ones-MFMA -> numerics parity).
// GEMMs untouched (control). Resubmitted unchanged (never ran: infra).

typedef __attribute__((ext_vector_type(8))) short bf16x8;   // 8 bf16 (MFMA A/B frag)
typedef __attribute__((ext_vector_type(4))) float f32x4;    // 16x16 MFMA C/D frag
typedef __attribute__((ext_vector_type(16))) float f32x16;  // 32x32 MFMA C/D frag
typedef __attribute__((ext_vector_type(2))) int int2v;

#define SEQ  4096
#define DM   512
#define FPAD 72    // Ks row stride (shorts): 64 d + pad (stride 36 dwords ≡ 4 mod 32)
#define VPAD 136   // Vs row stride (shorts): 128 kv + pad (68 dwords ≡ 4 mod 32)
#define QSCALE 0.18033688011112042f   // 0.125 * log2(e): scores in log2 domain
#define FSHIFT 16.0f                  // fixed softmax shift (log2 domain)

__device__ inline float fast_exp2(float x) {   // raw v_exp_f32: D = 2^S0
#if __has_builtin(__builtin_amdgcn_exp2f)
    return __builtin_amdgcn_exp2f(x);
#else
    return __expf(x * 0.69314718056f);
#endif
}

__device__ inline unsigned pk2(float x, float y) {   // 2x f32 -> packed bf16 RNE
#if __has_builtin(__builtin_amdgcn_cvt_pk_bf16_f32)
    typedef __attribute__((ext_vector_type(2))) __bf16 bf16x2_t;
    bf16x2_t h = __builtin_amdgcn_cvt_pk_bf16_f32(x, y);
    return *(unsigned*)&h;
#else
    unsigned ux = __float_as_uint(x);
    unsigned uy = __float_as_uint(y);
    ux += 0x7fff + ((ux >> 16) & 1);      // finite-safe RNE (all inputs finite)
    uy += 0x7fff + ((uy >> 16) & 1);
    return (ux >> 16) | (uy & 0xffff0000u);
#endif
}

// Swap a's upper 32 lanes with b's lower 32 lanes (VALU, no LDS traffic).
// ret.x = {a[0:31], b[0:31]}, ret.y = {a[32:63], b[32:63]}.
__device__ inline int2v swap_half(unsigned a, unsigned b, int h) {
#if __has_builtin(__builtin_amdgcn_permlane32_swap)
    (void)h;
    return __builtin_amdgcn_permlane32_swap((int)a, (int)b, false, false);
#else
    unsigned ax = (unsigned)__shfl_xor((int)a, 32);
    unsigned bx = (unsigned)__shfl_xor((int)b, 32);
    int2v r;
    r.x = h ? (int)bx : (int)a;
    r.y = h ? (int)b  : (int)ax;
    return r;
#endif
}

// Convert the 4 weight matrices (512x512 fp32) to bf16 once.
__global__ __launch_bounds__(256) void cvt_w(
    const float* __restrict__ w0, const float* __restrict__ w1,
    const float* __restrict__ w2, const float* __restrict__ w3,
    __hip_bfloat16* __restrict__ o0, __hip_bfloat16* __restrict__ o1,
    __hip_bfloat16* __restrict__ o2, __hip_bfloat16* __restrict__ o3)
{
    const float* w = (blockIdx.y == 0) ? w0 : (blockIdx.y == 1) ? w1
                   : (blockIdx.y == 2) ? w2 : w3;
    __hip_bfloat16* o = (blockIdx.y == 0) ? o0 : (blockIdx.y == 1) ? o1
                      : (blockIdx.y == 2) ? o2 : o3;
    const int i = (blockIdx.x * 256 + threadIdx.x) * 4;   // < 262144
    float4 v = *(const float4*)&w[i];
    uint2 p;
    p.x = pk2(v.x, v.y);
    p.y = pk2(v.z, v.w);
    *(uint2*)&((unsigned short*)o)[i] = p;
}

// Fused QKV projection (R9 structure), 64(M) x 128(N) tile, z selects stream.
__global__ __launch_bounds__(256) void qkv_proj(
    const float* __restrict__ Xq, const float* __restrict__ Xk, const float* __restrict__ Xv,
    const __hip_bfloat16* __restrict__ Wq16, const __hip_bfloat16* __restrict__ Wk16,
    const __hip_bfloat16* __restrict__ Wv16,
    const float* __restrict__ bq, const float* __restrict__ bk, const float* __restrict__ bv,
    __hip_bfloat16* __restrict__ Oq, __hip_bfloat16* __restrict__ Ok,
    __hip_bfloat16* __restrict__ Ovt)
{
    const int z = blockIdx.z;
    const float* A          = (z == 0) ? Xq : (z == 1) ? Xk : Xv;
    const __hip_bfloat16* W = (z == 0) ? Wq16 : (z == 1) ? Wk16 : Wv16;
    const float* bias       = (z == 0) ? bq : (z == 1) ? bk : bv;

    __shared__ __align__(16) short As[64 * 32];
    __shared__ __align__(16) short Ws2[128 * 32];

    const int bm   = blockIdx.x * 64;
    const int bn   = blockIdx.y * 128;
    const int tid  = threadIdx.x;
    const int wave = tid >> 6;
    const int lane = tid & 63;
    const int quad = lane >> 4;
    const int l16  = lane & 15;

    const int srow = tid >> 2;          // 0..63
    const int scol = (tid & 3) * 8;     // 0/8/16/24

    f32x4 acc[8] = {};

    float4 a0 = *(const float4*)&A[(size_t)(bm + srow) * DM + scol];
    float4 a1 = *(const float4*)&A[(size_t)(bm + srow) * DM + scol + 4];
    bf16x8 w0 = *(const bf16x8*)&W[(size_t)(bn + srow) * DM + scol];
    bf16x8 w1 = *(const bf16x8*)&W[(size_t)(bn + srow + 64) * DM + scol];

    for (int k0 = 0; k0 < DM; k0 += 32) {
        uint4 pa = {pk2(a0.x, a0.y), pk2(a0.z, a0.w), pk2(a1.x, a1.y), pk2(a1.z, a1.w)};

        __syncthreads();
        *(uint4*)&As[srow * 32 + scol] = pa;
        *(bf16x8*)&Ws2[srow * 32 + scol] = w0;
        *(bf16x8*)&Ws2[(srow + 64) * 32 + scol] = w1;
        __syncthreads();

        if (k0 + 32 < DM) {
            a0 = *(const float4*)&A[(size_t)(bm + srow) * DM + k0 + 32 + scol];
            a1 = *(const float4*)&A[(size_t)(bm + srow) * DM + k0 + 32 + scol + 4];
            w0 = *(const bf16x8*)&W[(size_t)(bn + srow) * DM + k0 + 32 + scol];
            w1 = *(const bf16x8*)&W[(size_t)(bn + srow + 64) * DM + k0 + 32 + scol];
        }

        bf16x8 a = *(bf16x8*)&As[(wave * 16 + l16) * 32 + quad * 8];
#pragma unroll
        for (int nt = 0; nt < 8; nt++) {
            bf16x8 b = *(bf16x8*)&Ws2[(nt * 16 + l16) * 32 + quad * 8];
            acc[nt] = __builtin_amdgcn_mfma_f32_16x16x32_bf16(a, b, acc[nt], 0, 0, 0);
        }
    }

    // C/D layout: col = lane&15 (= n), row = quad*4 + r (= m)
    if (z == 2) {
        const int row0 = bm + wave * 16 + quad * 4;
        const int b    = row0 >> 12;
        const int seq0 = row0 & 4095;
        unsigned short* Vt = (unsigned short*)Ovt;
#pragma unroll
        for (int nt = 0; nt < 8; nt++) {
            const int col = bn + nt * 16 + l16;
            const float bv_ = bias[col];
            uint2 pk;
            pk.x = pk2(acc[nt][0] + bv_, acc[nt][1] + bv_);
            pk.y = pk2(acc[nt][2] + bv_, acc[nt][3] + bv_);
            *(uint2*)&Vt[((size_t)(b * 512 + col)) * 4096 + seq0] = pk;
        }
    } else {
        unsigned short* C = (unsigned short*)((z == 0) ? Oq : Ok);
        const float scale = (z == 0) ? QSCALE : 1.0f;
        const size_t row0 = bm + wave * 16 + quad * 4;
#pragma unroll
        for (int nt = 0; nt < 8; nt++) {
            const int col = bn + nt * 16 + l16;
            const float bv_ = bias[col];
            unsigned u01 = pk2((acc[nt][0] + bv_) * scale, (acc[nt][1] + bv_) * scale);
            unsigned u23 = pk2((acc[nt][2] + bv_) * scale, (acc[nt][3] + bv_) * scale);
            C[(row0 + 0) * DM + col] = (unsigned short)(u01 & 0xffff);
            C[(row0 + 1) * DM + col] = (unsigned short)(u01 >> 16);
            C[(row0 + 2) * DM + col] = (unsigned short)(u23 & 0xffff);
            C[(row0 + 3) * DM + col] = (unsigned short)(u23 >> 16);
        }
    }
}

// Flash attention R17: 32x32x16 MFMA, 4 waves x 32 q, KV tile 128.
// S^T = K Q^T per 32-kv block; P rebuilt in-register (permlane32_swap) into
// the exact PV B-fragment layout; O^T += V^T P^T.
// 32x32x16 layouts (gfx950): A row = lane&31, k = (lane>>5)*8 + e;
// B col = lane&31, k = (lane>>5)*8 + e; C/D col = lane&31,
// row = (reg&3) + 8*(reg>>2) + 4*(lane>>5)   [m74/m101-verified].
__global__ __launch_bounds__(256, 4) void flash_attn(
    const __hip_bfloat16* __restrict__ Q,
    const __hip_bfloat16* __restrict__ K,
    const __hip_bfloat16* __restrict__ Vt,
    __hip_bfloat16* __restrict__ O)
{
    __shared__ __align__(16) short Ks[128 * FPAD];   // [kv 128][d 64]
    __shared__ __align__(16) short Vs[64 * VPAD];    // [dv 64][kv 128] (pre-transposed)

    const int q0  = blockIdx.x * 128;
    const int bh  = blockIdx.y;
    const int tid = threadIdx.x;
    const int wave = tid >> 6;      // 0..3
    const int lane = tid & 63;
    const int L = lane & 31;
    const int h = lane >> 5;

    const __hip_bfloat16* Qb = Q + (size_t)(bh >> 3) * SEQ * DM + (bh & 7) * 64;
    const __hip_bfloat16* Kb = K + (size_t)(bh >> 3) * SEQ * DM + (bh & 7) * 64;
    const __hip_bfloat16* Vb = Vt + (size_t)bh * 64 * SEQ;
    __hip_bfloat16*       Ob = O + (size_t)(bh >> 3) * SEQ * DM + (bh & 7) * 64;

    // staging maps (256 threads): K 128x64 in 4 rounds, V^T 64x128 in 4 rounds
    const int kr = tid >> 3;            // 0..31: K rows kr + i*32
    const int kc = (tid & 7) * 8;       // 64 d in 8 chunks
    const int vr = tid >> 4;            // 0..15: V rows vr + i*16
    const int vc = (tid & 15) * 8;      // 128 kv in 16 chunks

    // Q B-frags direct from global (one-time; never staged in LDS)
    const int qrow = q0 + wave * 32 + L;
    bf16x8 bq[4];
#pragma unroll
    for (int db = 0; db < 4; db++)
        bq[db] = *(const bf16x8*)&Qb[(size_t)qrow * DM + db * 16 + h * 8];

    // running global prefetch pointers
    const __hip_bfloat16* kg = Kb + (size_t)kr * DM + kc;
    const __hip_bfloat16* vg = Vb + (size_t)vr * SEQ + vc;

    bf16x8 kp[4], vp[4];
#pragma unroll
    for (int i = 0; i < 4; i++) {
        kp[i] = *(const bf16x8*)(kg + (size_t)i * 32 * DM);
        vp[i] = *(const bf16x8*)(vg + (size_t)i * 16 * SEQ);
    }

    // hoisted LDS bases (uniform-stride reads, bank-spread via FPAD/VPAD)
    const short* ksb = &Ks[L * FPAD + h * 8];
    const short* vsb = &Vs[L * VPAD + h * 8];

    f32x16 oacc[2] = {};   // O^T: dv = 32*dvb + (reg&3)+8*(reg>>2)+4h, col q = L
    float lsum = 0.0f;     // per-(lane,q) denominator partial (own 16 rows/32)

    for (int kv0 = 0; kv0 < SEQ; kv0 += 128) {
        __syncthreads();
#pragma unroll
        for (int i = 0; i < 4; i++) {
            *(bf16x8*)&Ks[(kr + i * 32) * FPAD + kc] = kp[i];
            *(bf16x8*)&Vs[(vr + i * 16) * VPAD + vc] = vp[i];
        }
        __syncthreads();

        kg += (size_t)128 * DM;
        vg += 128;
        if (kv0 + 128 < SEQ) {
#pragma unroll
            for (int i = 0; i < 4; i++) {
                kp[i] = *(const bf16x8*)(kg + (size_t)i * 32 * DM);
                vp[i] = *(const bf16x8*)(vg + (size_t)i * 16 * SEQ);
            }
        }

#pragma unroll
        for (int kb = 0; kb < 4; kb++) {
            // S^T (32 kv x 32 q) over d = 64 in four K=16 steps
            f32x16 s = {};
            __builtin_amdgcn_s_setprio(1);
#pragma unroll
            for (int db = 0; db < 4; db++) {
                bf16x8 ak = *(const bf16x8*)&ksb[(kb * 32) * FPAD + db * 16];
                s = __builtin_amdgcn_mfma_f32_32x32x16_bf16(ak, bq[db], s, 0, 0, 0);
            }
            __builtin_amdgcn_s_setprio(0);

            // P = 2^(s - 16) in place (exact by shift-invariance)
#pragma unroll
            for (int r = 0; r < 16; r++) s[r] = fast_exp2(s[r] - FSHIFT);

            // pack pairs of consecutive rows: pk_[j] = bf16(p[2j]) | bf16(p[2j+1])<<16
            unsigned pk_[8];
#pragma unroll
            for (int j = 0; j < 8; j++) pk_[j] = pk2(s[2 * j], s[2 * j + 1]);

            // denominator: sum of the SAME bf16-rounded terms (parity with
            // the old ones-MFMA reduction)
#pragma unroll
            for (int j = 0; j < 8; j++)
                lsum += __uint_as_float(pk_[j] << 16)
                      + __uint_as_float(pk_[j] & 0xffff0000u);

            // cross-half redistribution -> PV B-frags (VALU, no LDS):
            // frag g covers kv = kb*32 + 16g + 8h + (0..7)
            int2v w0 = swap_half(pk_[0], pk_[2], h);   // g0: d0 / d2
            int2v w1 = swap_half(pk_[1], pk_[3], h);   // g0: d1 / d3
            int2v w2 = swap_half(pk_[4], pk_[6], h);   // g1: d0 / d2
            int2v w3 = swap_half(pk_[5], pk_[7], h);   // g1: d1 / d3
            uint4 f0u = {(unsigned)w0.x, (unsigned)w1.x, (unsigned)w0.y, (unsigned)w1.y};
            uint4 f1u = {(unsigned)w2.x, (unsigned)w3.x, (unsigned)w2.y, (unsigned)w3.y};
            bf16x8 fg0 = *(bf16x8*)&f0u;
            bf16x8 fg1 = *(bf16x8*)&f1u;

            // O^T += V^T P^T for this 32-kv block
            __builtin_amdgcn_s_setprio(1);
#pragma unroll
            for (int dvb = 0; dvb < 2; dvb++) {
                bf16x8 av0 = *(const bf16x8*)&vsb[(dvb * 32) * VPAD + kb * 32];
                bf16x8 av1 = *(const bf16x8*)&vsb[(dvb * 32) * VPAD + kb * 32 + 16];
                oacc[dvb] = __builtin_amdgcn_mfma_f32_32x32x16_bf16(av0, fg0, oacc[dvb], 0, 0, 0);
                oacc[dvb] = __builtin_amdgcn_mfma_f32_32x32x16_bf16(av1, fg1, oacc[dvb], 0, 0, 0);
            }
            __builtin_amdgcn_s_setprio(0);
        }
    }

    // combine the two half-wave denominator partials (same q col at lane^32)
    const float tot = lsum + __shfl_xor(lsum, 32);
    const float inv = 1.0f / tot;

    // epilogue: lane owns q = qrow; dv = 32*dvb + 8*b + 4*h + r (r = 0..3)
    unsigned short* Op = (unsigned short*)Ob;
#pragma unroll
    for (int dvb = 0; dvb < 2; dvb++)
#pragma unroll
        for (int b = 0; b < 4; b++) {
            uint2 ov;
            ov.x = pk2(oacc[dvb][4 * b + 0] * inv, oacc[dvb][4 * b + 1] * inv);
            ov.y = pk2(oacc[dvb][4 * b + 2] * inv, oacc[dvb][4 * b + 3] * inv);
            *(uint2*)&Op[(size_t)qrow * DM + dvb * 32 + b * 8 + h * 4] = ov;
        }
}

// Output projection (R9 structure), 64x128 tile: A bf16, W bf16, C fp32.
__global__ __launch_bounds__(256) void out_proj(
    const __hip_bfloat16* __restrict__ A,
    const __hip_bfloat16* __restrict__ W,
    const float* __restrict__ bias,
    float* __restrict__ C)
{
    __shared__ __align__(16) short As[64 * 32];
    __shared__ __align__(16) short Ws2[128 * 32];

    const int bm   = blockIdx.x * 64;
    const int bn   = blockIdx.y * 128;
    const int tid  = threadIdx.x;
    const int wave = tid >> 6;
    const int lane = tid & 63;
    const int quad = lane >> 4;
    const int l16  = lane & 15;

    const int srow = tid >> 2;
    const int scol = (tid & 3) * 8;

    f32x4 acc[8] = {};

    bf16x8 ap = *(const bf16x8*)&A[(size_t)(bm + srow) * DM + scol];
    bf16x8 w0 = *(const bf16x8*)&W[(size_t)(bn + srow) * DM + scol];
    bf16x8 w1 = *(const bf16x8*)&W[(size_t)(bn + srow + 64) * DM + scol];

    for (int k0 = 0; k0 < DM; k0 += 32) {
        __syncthreads();
        *(bf16x8*)&As[srow * 32 + scol] = ap;
        *(bf16x8*)&Ws2[srow * 32 + scol] = w0;
        *(bf16x8*)&Ws2[(srow + 64) * 32 + scol] = w1;
        __syncthreads();

        if (k0 + 32 < DM) {
            ap = *(const bf16x8*)&A[(size_t)(bm + srow) * DM + k0 + 32 + scol];
            w0 = *(const bf16x8*)&W[(size_t)(bn + srow) * DM + k0 + 32 + scol];
            w1 = *(const bf16x8*)&W[(size_t)(bn + srow + 64) * DM + k0 + 32 + scol];
        }

        bf16x8 a = *(bf16x8*)&As[(wave * 16 + l16) * 32 + quad * 8];
#pragma unroll
        for (int nt = 0; nt < 8; nt++) {
            bf16x8 b = *(bf16x8*)&Ws2[(nt * 16 + l16) * 32 + quad * 8];
            acc[nt] = __builtin_amdgcn_mfma_f32_16x16x32_bf16(a, b, acc[nt], 0, 0, 0);
        }
    }

#pragma unroll
    for (int nt = 0; nt < 8; nt++) {
        const int col = bn + nt * 16 + l16;
        const float bv_ = bias[col];
#pragma unroll
        for (int r = 0; r < 4; r++) {
            const int row = bm + wave * 16 + quad * 4 + r;
            C[(size_t)row * DM + col] = acc[nt][r] + bv_;
        }
    }
}

extern "C" void kernel_launch(void* const* d_in, const int* in_sizes, int n_in,
                              void* d_out, int out_size, void* d_ws, size_t ws_size,
                              hipStream_t stream) {
    const float* queries = (const float*)d_in[0];
    const float* keys    = (const float*)d_in[1];
    const float* values  = (const float*)d_in[2];
    const float* Wq = (const float*)d_in[3];
    const float* bq = (const float*)d_in[4];
    const float* Wk = (const float*)d_in[5];
    const float* bk = (const float*)d_in[6];
    const float* Wv = (const float*)d_in[7];
    const float* bv = (const float*)d_in[8];
    const float* Wo = (const float*)d_in[9];
    const float* bo = (const float*)d_in[10];
    float* out = (float*)d_out;

    const size_t MS = (size_t)2 * SEQ * DM;   // 4.19M elems
    const size_t WN = (size_t)DM * DM;        // 262144 elems
    __hip_bfloat16* q_ws  = (__hip_bfloat16*)d_ws;
    __hip_bfloat16* k_ws  = q_ws + MS;
    __hip_bfloat16* vt_ws = k_ws + MS;        // [16][64][4096]
    __hip_bfloat16* o_ws  = vt_ws + MS;
    __hip_bfloat16* wq16  = o_ws + MS;
    __hip_bfloat16* wk16  = wq16 + WN;
    __hip_bfloat16* wv16  = wk16 + WN;
    __hip_bfloat16* wo16  = wv16 + WN;

    dim3 blk(256);

    cvt_w<<<dim3(256, 4), blk, 0, stream>>>(Wq, Wk, Wv, Wo, wq16, wk16, wv16, wo16);

    qkv_proj<<<dim3(128, 4, 3), blk, 0, stream>>>(
        queries, keys, values, wq16, wk16, wv16, bq, bk, bv, q_ws, k_ws, vt_ws);

    flash_attn<<<dim3(32, 16), blk, 0, stream>>>(q_ws, k_ws, vt_ws, o_ws);

    out_proj<<<dim3(128, 4), blk, 0, stream>>>(o_ws, wo16, bo, out);
}

// Round 10
// 236.226 us; speedup vs baseline: 1.0645x; 1.0640x over previous
//
#include <hip/hip_runtime.h>
#include <hip/hip_bf16.h>

// MHA: weight pre-convert -> fused qkv proj (R9/R11 64x128) -> flash attention
// -> out proj.
// R21/R22: flash occupancy x2 + VALU thinning (R17 post-mortem: LDS fixed
// [conflicts 23.1M->0] but dur flat -> limiter = 2 waves/SIMD + VALU 55%):
//   * 8 waves/block (512 thr): waves split the 4 kb sub-blocks per staged
//     KV tile (kvg = wave>>2 -> kb {0,1} vs {2,3}); single Ks/Vs buffer
//     unchanged -> 16 waves/CU = 4 waves/SIMD.
//   * cross-group partials combined once at end via LDS (reuse Ks/Vs).
//   * FSHIFT folded into MFMA acc init (s starts at -16): -16 VALU/kb.
//   * denominator summed from unrounded f32 P (RNE-unbiased): -16 VALU/kb.
// GEMMs untouched (control). Resubmitted unchanged (R21 never ran: timeout).

typedef __attribute__((ext_vector_type(8))) short bf16x8;   // 8 bf16 (MFMA A/B frag)
typedef __attribute__((ext_vector_type(4))) float f32x4;    // 16x16 MFMA C/D frag
typedef __attribute__((ext_vector_type(16))) float f32x16;  // 32x32 MFMA C/D frag
typedef __attribute__((ext_vector_type(2))) int int2v;

#define SEQ  4096
#define DM   512
#define FPAD 72    // Ks row stride (shorts): 64 d + pad
#define VPAD 136   // Vs row stride (shorts): 128 kv + pad
#define QSCALE 0.18033688011112042f   // 0.125 * log2(e): scores in log2 domain
#define FSHIFT 16.0f                  // fixed softmax shift (log2 domain)

__device__ inline float fast_exp2(float x) {   // raw v_exp_f32: D = 2^S0
#if __has_builtin(__builtin_amdgcn_exp2f)
    return __builtin_amdgcn_exp2f(x);
#else
    return __expf(x * 0.69314718056f);
#endif
}

__device__ inline unsigned pk2(float x, float y) {   // 2x f32 -> packed bf16 RNE
#if __has_builtin(__builtin_amdgcn_cvt_pk_bf16_f32)
    typedef __attribute__((ext_vector_type(2))) __bf16 bf16x2_t;
    bf16x2_t h = __builtin_amdgcn_cvt_pk_bf16_f32(x, y);
    return *(unsigned*)&h;
#else
    unsigned ux = __float_as_uint(x);
    unsigned uy = __float_as_uint(y);
    ux += 0x7fff + ((ux >> 16) & 1);      // finite-safe RNE (all inputs finite)
    uy += 0x7fff + ((uy >> 16) & 1);
    return (ux >> 16) | (uy & 0xffff0000u);
#endif
}

// Swap a's upper 32 lanes with b's lower 32 lanes (VALU, no LDS traffic).
__device__ inline int2v swap_half(unsigned a, unsigned b, int h) {
#if __has_builtin(__builtin_amdgcn_permlane32_swap)
    (void)h;
    return __builtin_amdgcn_permlane32_swap((int)a, (int)b, false, false);
#else
    unsigned ax = (unsigned)__shfl_xor((int)a, 32);
    unsigned bx = (unsigned)__shfl_xor((int)b, 32);
    int2v r;
    r.x = h ? (int)bx : (int)a;
    r.y = h ? (int)b  : (int)ax;
    return r;
#endif
}

// Convert the 4 weight matrices (512x512 fp32) to bf16 once.
__global__ __launch_bounds__(256) void cvt_w(
    const float* __restrict__ w0, const float* __restrict__ w1,
    const float* __restrict__ w2, const float* __restrict__ w3,
    __hip_bfloat16* __restrict__ o0, __hip_bfloat16* __restrict__ o1,
    __hip_bfloat16* __restrict__ o2, __hip_bfloat16* __restrict__ o3)
{
    const float* w = (blockIdx.y == 0) ? w0 : (blockIdx.y == 1) ? w1
                   : (blockIdx.y == 2) ? w2 : w3;
    __hip_bfloat16* o = (blockIdx.y == 0) ? o0 : (blockIdx.y == 1) ? o1
                      : (blockIdx.y == 2) ? o2 : o3;
    const int i = (blockIdx.x * 256 + threadIdx.x) * 4;   // < 262144
    float4 v = *(const float4*)&w[i];
    uint2 p;
    p.x = pk2(v.x, v.y);
    p.y = pk2(v.z, v.w);
    *(uint2*)&((unsigned short*)o)[i] = p;
}

// Fused QKV projection (R9 structure), 64(M) x 128(N) tile, z selects stream.
__global__ __launch_bounds__(256) void qkv_proj(
    const float* __restrict__ Xq, const float* __restrict__ Xk, const float* __restrict__ Xv,
    const __hip_bfloat16* __restrict__ Wq16, const __hip_bfloat16* __restrict__ Wk16,
    const __hip_bfloat16* __restrict__ Wv16,
    const float* __restrict__ bq, const float* __restrict__ bk, const float* __restrict__ bv,
    __hip_bfloat16* __restrict__ Oq, __hip_bfloat16* __restrict__ Ok,
    __hip_bfloat16* __restrict__ Ovt)
{
    const int z = blockIdx.z;
    const float* A          = (z == 0) ? Xq : (z == 1) ? Xk : Xv;
    const __hip_bfloat16* W = (z == 0) ? Wq16 : (z == 1) ? Wk16 : Wv16;
    const float* bias       = (z == 0) ? bq : (z == 1) ? bk : bv;

    __shared__ __align__(16) short As[64 * 32];
    __shared__ __align__(16) short Ws2[128 * 32];

    const int bm   = blockIdx.x * 64;
    const int bn   = blockIdx.y * 128;
    const int tid  = threadIdx.x;
    const int wave = tid >> 6;
    const int lane = tid & 63;
    const int quad = lane >> 4;
    const int l16  = lane & 15;

    const int srow = tid >> 2;          // 0..63
    const int scol = (tid & 3) * 8;     // 0/8/16/24

    f32x4 acc[8] = {};

    float4 a0 = *(const float4*)&A[(size_t)(bm + srow) * DM + scol];
    float4 a1 = *(const float4*)&A[(size_t)(bm + srow) * DM + scol + 4];
    bf16x8 w0 = *(const bf16x8*)&W[(size_t)(bn + srow) * DM + scol];
    bf16x8 w1 = *(const bf16x8*)&W[(size_t)(bn + srow + 64) * DM + scol];

    for (int k0 = 0; k0 < DM; k0 += 32) {
        uint4 pa = {pk2(a0.x, a0.y), pk2(a0.z, a0.w), pk2(a1.x, a1.y), pk2(a1.z, a1.w)};

        __syncthreads();
        *(uint4*)&As[srow * 32 + scol] = pa;
        *(bf16x8*)&Ws2[srow * 32 + scol] = w0;
        *(bf16x8*)&Ws2[(srow + 64) * 32 + scol] = w1;
        __syncthreads();

        if (k0 + 32 < DM) {
            a0 = *(const float4*)&A[(size_t)(bm + srow) * DM + k0 + 32 + scol];
            a1 = *(const float4*)&A[(size_t)(bm + srow) * DM + k0 + 32 + scol + 4];
            w0 = *(const bf16x8*)&W[(size_t)(bn + srow) * DM + k0 + 32 + scol];
            w1 = *(const bf16x8*)&W[(size_t)(bn + srow + 64) * DM + k0 + 32 + scol];
        }

        bf16x8 a = *(bf16x8*)&As[(wave * 16 + l16) * 32 + quad * 8];
#pragma unroll
        for (int nt = 0; nt < 8; nt++) {
            bf16x8 b = *(bf16x8*)&Ws2[(nt * 16 + l16) * 32 + quad * 8];
            acc[nt] = __builtin_amdgcn_mfma_f32_16x16x32_bf16(a, b, acc[nt], 0, 0, 0);
        }
    }

    // C/D layout: col = lane&15 (= n), row = quad*4 + r (= m)
    if (z == 2) {
        const int row0 = bm + wave * 16 + quad * 4;
        const int b    = row0 >> 12;
        const int seq0 = row0 & 4095;
        unsigned short* Vt = (unsigned short*)Ovt;
#pragma unroll
        for (int nt = 0; nt < 8; nt++) {
            const int col = bn + nt * 16 + l16;
            const float bv_ = bias[col];
            uint2 pk;
            pk.x = pk2(acc[nt][0] + bv_, acc[nt][1] + bv_);
            pk.y = pk2(acc[nt][2] + bv_, acc[nt][3] + bv_);
            *(uint2*)&Vt[((size_t)(b * 512 + col)) * 4096 + seq0] = pk;
        }
    } else {
        unsigned short* C = (unsigned short*)((z == 0) ? Oq : Ok);
        const float scale = (z == 0) ? QSCALE : 1.0f;
        const size_t row0 = bm + wave * 16 + quad * 4;
#pragma unroll
        for (int nt = 0; nt < 8; nt++) {
            const int col = bn + nt * 16 + l16;
            const float bv_ = bias[col];
            unsigned u01 = pk2((acc[nt][0] + bv_) * scale, (acc[nt][1] + bv_) * scale);
            unsigned u23 = pk2((acc[nt][2] + bv_) * scale, (acc[nt][3] + bv_) * scale);
            C[(row0 + 0) * DM + col] = (unsigned short)(u01 & 0xffff);
            C[(row0 + 1) * DM + col] = (unsigned short)(u01 >> 16);
            C[(row0 + 2) * DM + col] = (unsigned short)(u23 & 0xffff);
            C[(row0 + 3) * DM + col] = (unsigned short)(u23 >> 16);
        }
    }
}

// Flash attention R21: 32x32x16 MFMA, 8 waves x 32 q (q-group = wave&3,
// kv-group = wave>>2 splits the 4 kb sub-blocks of each staged 128-kv tile).
// Single Ks/Vs buffer; partial O/l combined across kv-groups at end via LDS.
// 32x32x16 layouts (gfx950): A row = lane&31, k = (lane>>5)*8 + e;
// B col = lane&31, k = (lane>>5)*8 + e; C/D col = lane&31,
// row = (reg&3) + 8*(reg>>2) + 4*(lane>>5)   [m74/m101-verified].
__global__ __launch_bounds__(512, 4) void flash_attn(
    const __hip_bfloat16* __restrict__ Q,
    const __hip_bfloat16* __restrict__ K,
    const __hip_bfloat16* __restrict__ Vt,
    __hip_bfloat16* __restrict__ O)
{
    __shared__ __align__(16) short Ks[128 * FPAD];   // [kv 128][d 64]
    __shared__ __align__(16) short Vs[64 * VPAD];    // [dv 64][kv 128] (pre-transposed)

    const int q0  = blockIdx.x * 128;
    const int bh  = blockIdx.y;
    const int tid = threadIdx.x;
    const int wave = tid >> 6;      // 0..7
    const int lane = tid & 63;
    const int L = lane & 31;
    const int h = lane >> 5;
    const int qg  = wave & 3;       // q-group: q = q0 + qg*32 + L
    const int kvg = wave >> 2;      // kv-group: kb in {2*kvg, 2*kvg+1}

    const __hip_bfloat16* Qb = Q + (size_t)(bh >> 3) * SEQ * DM + (bh & 7) * 64;
    const __hip_bfloat16* Kb = K + (size_t)(bh >> 3) * SEQ * DM + (bh & 7) * 64;
    const __hip_bfloat16* Vb = Vt + (size_t)bh * 64 * SEQ;
    __hip_bfloat16*       Ob = O + (size_t)(bh >> 3) * SEQ * DM + (bh & 7) * 64;

    // staging maps (512 threads): K 128x64 in 2 rounds, V^T 64x128 in 2 rounds
    const int kr = tid >> 3;            // 0..63: K rows kr, kr+64
    const int kc = (tid & 7) * 8;       // 64 d in 8 chunks
    const int vr = tid >> 4;            // 0..31: V rows vr, vr+32
    const int vc = (tid & 15) * 8;      // 128 kv in 16 chunks

    // Q B-frags direct from global (one-time; never staged in LDS)
    const int qrow = q0 + qg * 32 + L;
    bf16x8 bq[4];
#pragma unroll
    for (int db = 0; db < 4; db++)
        bq[db] = *(const bf16x8*)&Qb[(size_t)qrow * DM + db * 16 + h * 8];

    // running global prefetch pointers
    const __hip_bfloat16* kg = Kb + (size_t)kr * DM + kc;
    const __hip_bfloat16* vg = Vb + (size_t)vr * SEQ + vc;

    bf16x8 kp[2], vp[2];
    kp[0] = *(const bf16x8*)(kg);
    kp[1] = *(const bf16x8*)(kg + (size_t)64 * DM);
    vp[0] = *(const bf16x8*)(vg);
    vp[1] = *(const bf16x8*)(vg + (size_t)32 * SEQ);

    // hoisted LDS bases
    const short* ksb = &Ks[L * FPAD + h * 8];
    const short* vsb = &Vs[L * VPAD + h * 8];

    f32x16 oacc[2] = {};   // O^T partial: dv = 32*dvb + (reg&3)+8*(reg>>2)+4h, q = L
    float l0 = 0.0f, l1 = 0.0f;   // denominator partials (2 accums for ILP)

    for (int kv0 = 0; kv0 < SEQ; kv0 += 128) {
        __syncthreads();
        *(bf16x8*)&Ks[kr * FPAD + kc] = kp[0];
        *(bf16x8*)&Ks[(kr + 64) * FPAD + kc] = kp[1];
        *(bf16x8*)&Vs[vr * VPAD + vc] = vp[0];
        *(bf16x8*)&Vs[(vr + 32) * VPAD + vc] = vp[1];
        __syncthreads();

        kg += (size_t)128 * DM;
        vg += 128;
        if (kv0 + 128 < SEQ) {
            kp[0] = *(const bf16x8*)(kg);
            kp[1] = *(const bf16x8*)(kg + (size_t)64 * DM);
            vp[0] = *(const bf16x8*)(vg);
            vp[1] = *(const bf16x8*)(vg + (size_t)32 * SEQ);
        }

#pragma unroll
        for (int kb2 = 0; kb2 < 2; kb2++) {
            const int kb = kvg * 2 + kb2;
            // S^T (32 kv x 32 q) over d = 64; FSHIFT folded into acc init
            f32x16 s;
#pragma unroll
            for (int r = 0; r < 16; r++) s[r] = -FSHIFT;
            __builtin_amdgcn_s_setprio(1);
#pragma unroll
            for (int db = 0; db < 4; db++) {
                bf16x8 ak = *(const bf16x8*)&ksb[(kb * 32) * FPAD + db * 16];
                s = __builtin_amdgcn_mfma_f32_32x32x16_bf16(ak, bq[db], s, 0, 0, 0);
            }
            __builtin_amdgcn_s_setprio(0);

            // P = 2^s in place (s already includes -16 shift)
#pragma unroll
            for (int r = 0; r < 16; r++) s[r] = fast_exp2(s[r]);

            // denominator: unrounded f32 sum (RNE rounding is unbiased;
            // relative shift ~3e-5 over 4096 terms)
#pragma unroll
            for (int r = 0; r < 16; r += 2) { l0 += s[r]; l1 += s[r + 1]; }

            // pack pairs of consecutive rows
            unsigned pk_[8];
#pragma unroll
            for (int j = 0; j < 8; j++) pk_[j] = pk2(s[2 * j], s[2 * j + 1]);

            // cross-half redistribution -> PV B-frags (VALU, no LDS)
            int2v w0 = swap_half(pk_[0], pk_[2], h);
            int2v w1 = swap_half(pk_[1], pk_[3], h);
            int2v w2 = swap_half(pk_[4], pk_[6], h);
            int2v w3 = swap_half(pk_[5], pk_[7], h);
            uint4 f0u = {(unsigned)w0.x, (unsigned)w1.x, (unsigned)w0.y, (unsigned)w1.y};
            uint4 f1u = {(unsigned)w2.x, (unsigned)w3.x, (unsigned)w2.y, (unsigned)w3.y};
            bf16x8 fg0 = *(bf16x8*)&f0u;
            bf16x8 fg1 = *(bf16x8*)&f1u;

            // O^T += V^T P^T for this 32-kv block
            __builtin_amdgcn_s_setprio(1);
#pragma unroll
            for (int dvb = 0; dvb < 2; dvb++) {
                bf16x8 av0 = *(const bf16x8*)&vsb[(dvb * 32) * VPAD + kb * 32];
                bf16x8 av1 = *(const bf16x8*)&vsb[(dvb * 32) * VPAD + kb * 32 + 16];
                oacc[dvb] = __builtin_amdgcn_mfma_f32_32x32x16_bf16(av0, fg0, oacc[dvb], 0, 0, 0);
                oacc[dvb] = __builtin_amdgcn_mfma_f32_32x32x16_bf16(av1, fg1, oacc[dvb], 0, 0, 0);
            }
            __builtin_amdgcn_s_setprio(0);
        }
    }

    // per-wave denominator: combine the two half-wave partials (same q at lane^32)
    float lsum = l0 + l1;
    float tot = lsum + __shfl_xor(lsum, 32);

    // cross-kv-group combine via LDS (reuse Ks for qg 0,1; Vs for qg 2,3).
    // slot: 64 lanes x 33 floats per (qg&1) area-half.
    __syncthreads();   // all waves done reading Ks/Vs
    float* area = (qg < 2) ? (float*)Ks : (float*)Vs;
    float* slot = area + (qg & 1) * (64 * 33) + lane * 33;
    if (kvg == 1) {
#pragma unroll
        for (int dvb = 0; dvb < 2; dvb++)
#pragma unroll
            for (int r = 0; r < 16; r++) slot[dvb * 16 + r] = oacc[dvb][r];
        slot[32] = tot;
    }
    __syncthreads();
    if (kvg == 0) {
#pragma unroll
        for (int dvb = 0; dvb < 2; dvb++)
#pragma unroll
            for (int r = 0; r < 16; r++) oacc[dvb][r] += slot[dvb * 16 + r];
        tot += slot[32];

        const float inv = 1.0f / tot;
        // epilogue: lane owns q = qrow; dv = 32*dvb + 8*b + 4*h + r
        unsigned short* Op = (unsigned short*)Ob;
#pragma unroll
        for (int dvb = 0; dvb < 2; dvb++)
#pragma unroll
            for (int b = 0; b < 4; b++) {
                uint2 ov;
                ov.x = pk2(oacc[dvb][4 * b + 0] * inv, oacc[dvb][4 * b + 1] * inv);
                ov.y = pk2(oacc[dvb][4 * b + 2] * inv, oacc[dvb][4 * b + 3] * inv);
                *(uint2*)&Op[(size_t)qrow * DM + dvb * 32 + b * 8 + h * 4] = ov;
            }
    }
}

// Output projection (R9 structure), 64x128 tile: A bf16, W bf16, C fp32.
__global__ __launch_bounds__(256) void out_proj(
    const __hip_bfloat16* __restrict__ A,
    const __hip_bfloat16* __restrict__ W,
    const float* __restrict__ bias,
    float* __restrict__ C)
{
    __shared__ __align__(16) short As[64 * 32];
    __shared__ __align__(16) short Ws2[128 * 32];

    const int bm   = blockIdx.x * 64;
    const int bn   = blockIdx.y * 128;
    const int tid  = threadIdx.x;
    const int wave = tid >> 6;
    const int lane = tid & 63;
    const int quad = lane >> 4;
    const int l16  = lane & 15;

    const int srow = tid >> 2;
    const int scol = (tid & 3) * 8;

    f32x4 acc[8] = {};

    bf16x8 ap = *(const bf16x8*)&A[(size_t)(bm + srow) * DM + scol];
    bf16x8 w0 = *(const bf16x8*)&W[(size_t)(bn + srow) * DM + scol];
    bf16x8 w1 = *(const bf16x8*)&W[(size_t)(bn + srow + 64) * DM + scol];

    for (int k0 = 0; k0 < DM; k0 += 32) {
        __syncthreads();
        *(bf16x8*)&As[srow * 32 + scol] = ap;
        *(bf16x8*)&Ws2[srow * 32 + scol] = w0;
        *(bf16x8*)&Ws2[(srow + 64) * 32 + scol] = w1;
        __syncthreads();

        if (k0 + 32 < DM) {
            ap = *(const bf16x8*)&A[(size_t)(bm + srow) * DM + k0 + 32 + scol];
            w0 = *(const bf16x8*)&W[(size_t)(bn + srow) * DM + k0 + 32 + scol];
            w1 = *(const bf16x8*)&W[(size_t)(bn + srow + 64) * DM + k0 + 32 + scol];
        }

        bf16x8 a = *(bf16x8*)&As[(wave * 16 + l16) * 32 + quad * 8];
#pragma unroll
        for (int nt = 0; nt < 8; nt++) {
            bf16x8 b = *(bf16x8*)&Ws2[(nt * 16 + l16) * 32 + quad * 8];
            acc[nt] = __builtin_amdgcn_mfma_f32_16x16x32_bf16(a, b, acc[nt], 0, 0, 0);
        }
    }

#pragma unroll
    for (int nt = 0; nt < 8; nt++) {
        const int col = bn + nt * 16 + l16;
        const float bv_ = bias[col];
#pragma unroll
        for (int r = 0; r < 4; r++) {
            const int row = bm + wave * 16 + quad * 4 + r;
            C[(size_t)row * DM + col] = acc[nt][r] + bv_;
        }
    }
}

extern "C" void kernel_launch(void* const* d_in, const int* in_sizes, int n_in,
                              void* d_out, int out_size, void* d_ws, size_t ws_size,
                              hipStream_t stream) {
    const float* queries = (const float*)d_in[0];
    const float* keys    = (const float*)d_in[1];
    const float* values  = (const float*)d_in[2];
    const float* Wq = (const float*)d_in[3];
    const float* bq = (const float*)d_in[4];
    const float* Wk = (const float*)d_in[5];
    const float* bk = (const float*)d_in[6];
    const float* Wv = (const float*)d_in[7];
    const float* bv = (const float*)d_in[8];
    const float* Wo = (const float*)d_in[9];
    const float* bo = (const float*)d_in[10];
    float* out = (float*)d_out;

    const size_t MS = (size_t)2 * SEQ * DM;   // 4.19M elems
    const size_t WN = (size_t)DM * DM;        // 262144 elems
    __hip_bfloat16* q_ws  = (__hip_bfloat16*)d_ws;
    __hip_bfloat16* k_ws  = q_ws + MS;
    __hip_bfloat16* vt_ws = k_ws + MS;        // [16][64][4096]
    __hip_bfloat16* o_ws  = vt_ws + MS;
    __hip_bfloat16* wq16  = o_ws + MS;
    __hip_bfloat16* wk16  = wq16 + WN;
    __hip_bfloat16* wv16  = wk16 + WN;
    __hip_bfloat16* wo16  = wv16 + WN;

    dim3 blk(256);

    cvt_w<<<dim3(256, 4), blk, 0, stream>>>(Wq, Wk, Wv, Wo, wq16, wk16, wv16, wo16);

    qkv_proj<<<dim3(128, 4, 3), blk, 0, stream>>>(
        queries, keys, values, wq16, wk16, wv16, bq, bk, bv, q_ws, k_ws, vt_ws);

    flash_attn<<<dim3(32, 16), dim3(512), 0, stream>>>(q_ws, k_ws, vt_ws, o_ws);

    out_proj<<<dim3(128, 4), blk, 0, stream>>>(o_ws, wo16, bo, out);
}